// Round 23
// baseline (547.651 us; speedup 1.0000x reference)
//
#include <hip/hip_runtime.h>
#include <math.h>

#define N_NODES 100000
#define N_EDGES 400000
#define POSD 3
#define F 128
#define M 16
#define EIN 289
#define EHID 578
#define NIN 144
#define NHID 256
#define ROW 131
#define LNEPS 1e-5f

// edge GEMM dims — plain padded LDS, no swizzle
#define KPA 328     // A row stride: 320+8 (free 2-way bank alias)
#define NP 640
#define EPB 32      // edges per block (512 threads, 8 waves)
#define NSLICE 10
#define NTW 5
#define HIDP 640    // w2t K stride
#define HIDPA 648   // hid LDS row stride: 640+8

// node kernel — plain padded LDS (validated)
#define NPB2 80
#define NK1P 168
#define NSL2 5
#define NHIDP 264

// ws offsets (bytes)
#define WS_W1KS   6400000
#define WS_W2T    6809600
#define WS_FEATS  6830080
#define WS_W1KS2  32430080
#define WS_W2KS   32512000

typedef _Float16 half8 __attribute__((ext_vector_type(8)));
typedef _Float16 half4 __attribute__((ext_vector_type(4)));
typedef float f32x4 __attribute__((ext_vector_type(4)));

__device__ __forceinline__ float silu_f(float v) {
    return v * __builtin_amdgcn_rcpf(1.f + __expf(-v));
}

// ---------------- prep: x feats -> fp16 [N][128] ---------------------------
__global__ __launch_bounds__(256) void prep_feats(
    const float* __restrict__ x, _Float16* __restrict__ feats)
{
    long long i = (long long)blockIdx.x * 256 + threadIdx.x;
    if (i < (long long)N_NODES * F) {
        int n = (int)(i >> 7), k = (int)(i & 127);
        feats[i] = (_Float16)x[(long long)n * ROW + POSD + k];
    }
}

// ---------------- prep: edge weights fp16 -----------------------------------
__global__ __launch_bounds__(256) void prep_weights(
    const float* __restrict__ w1, const float* __restrict__ w2,
    _Float16* __restrict__ w1ks, _Float16* __restrict__ w2t)
{
    long long idx = (long long)blockIdx.x * 256 + threadIdx.x;
    const long long n1 = (long long)NSLICE * NP * 32;  // 204800
    if (idx < n1) {
        int s   = (int)(idx / (NP * 32));
        int rem = (int)(idx - (long long)s * (NP * 32));
        int c   = rem >> 5;
        int kk  = rem & 31;
        int k   = s * 32 + kk;
        float v = (k < EIN && c < EHID) ? w1[(long long)k * EHID + c] : 0.f;
        w1ks[idx] = (_Float16)v;   // (slice, col, kk) plain
    } else {
        long long j = idx - n1;
        if (j < (long long)M * HIDP) {
            int oc = (int)(j / HIDP);
            int k  = (int)(j - (long long)oc * HIDP);
            float v = (k < EHID) ? w2[(long long)k * M + oc] : 0.f;
            w2t[j] = (_Float16)v;
        }
    }
}

// ---------------- prep: node weights fp16 K-sliced --------------------------
__global__ __launch_bounds__(256) void prep_weights_node(
    const float* __restrict__ w1, const float* __restrict__ w2,
    _Float16* __restrict__ w1ks2, _Float16* __restrict__ w2ks)
{
    int idx = blockIdx.x * 256 + threadIdx.x;
    const int n1 = NSL2 * 256 * 32;  // 40960
    if (idx < n1) {
        int s = idx >> 13, rem = idx & 8191;
        int c = rem >> 5, kk = rem & 31;
        int k = s * 32 + kk;
        w1ks2[idx] = (_Float16)((k < NIN) ? w1[k * NHID + c] : 0.f);
    } else if (idx < n1 + 8 * 128 * 32) {
        int j = idx - n1;
        int s = j >> 12, rem = j & 4095;
        int c = rem >> 5, kk = rem & 31;
        int k = s * 32 + kk;
        w2ks[j] = (_Float16)w2[k * F + c];
    }
}

// ---------------- Edge kernel: GEMM1 2-deep B-prefetch, sched_barrier-pinned
// 16x16x32 layout: A row = lane&15, k-grp = lane>>4; B col = lane&15;
// C/D col = lane&15, row = (lane>>4)*4 + reg.
__global__ __launch_bounds__(512, 4) void edge_kernel(
    const _Float16* __restrict__ feats, const float* __restrict__ x,
    const int* __restrict__ ei,
    const _Float16* __restrict__ w1ks, const float* __restrict__ b1,
    const _Float16* __restrict__ w2t, const float* __restrict__ b2,
    const float* __restrict__ g1, const float* __restrict__ bb1,
    float* __restrict__ m_i)
{
    __shared__ __align__(16) _Float16 smem[EPB * HIDPA];  // 41472 B (union)
    _Float16* lds_A = smem;     // [32][328] plain, first 20992 B
    _Float16* lds_H = smem;     // [32][648] plain, full
    __shared__ float part[4][EPB][M];                     // 8192 B GEMM2 partials
    __shared__ int   src_s[EPB], dst_s[EPB];
    __shared__ float d_s[EPB];

    const int t    = threadIdx.x;
    const int lane = t & 63;
    const int wv   = t >> 6;       // 0..7
    const int cl16 = lane & 15;
    const int h4   = lane >> 4;
    const long long ebase = (long long)blockIdx.x * EPB;

    if (t < EPB) {
        int s = ei[ebase + t];
        int d = ei[(long long)N_EDGES + ebase + t];
        src_s[t] = s; dst_s[t] = d;
        float dx = x[(long long)s*ROW+0] - x[(long long)d*ROW+0];
        float dy = x[(long long)s*ROW+1] - x[(long long)d*ROW+1];
        float dz = x[(long long)s*ROW+2] - x[(long long)d*ROW+2];
        d_s[t] = dx*dx + dy*dy + dz*dz;
    }
    __syncthreads();

    // ---- A staging: feats, 16B half8 loads, plain 16B LDS writes
    for (int i = t; i < EPB * 32; i += 512) {
        int row = i >> 5, g = i & 31;
        int node = (g < 16) ? dst_s[row] : src_s[row];
        half8 v = *(const half8*)(feats + (long long)node * F + ((g & 15) << 3));
        *(half8*)(lds_A + row * KPA + (g << 3)) = v;
    }
    // ---- A staging: rbf + d + pad, branch-free
    for (int i = t; i < EPB * 64; i += 512) {
        int row = i >> 6, j = i & 63;
        float dv = d_s[row];
        float ds = ldexpf(dv, -(j & 15));
        float v = (j < 16) ? __sinf(ds) : (j < 32) ? __cosf(ds)
                : (j == 32) ? dv : 0.f;
        lds_A[row * KPA + 256 + j] = (_Float16)v;
    }
    __syncthreads();

    // ---- GEMM1: [32 x 320] @ [320 x 640]; 2-deep B prefetch pinned with
    //      sched_barrier(0) so the compiler cannot sink the loads (rounds
    //      12/13/14: without the fence it always sank them -> VGPR 40).
    f32x4 acc[2][NTW] = {};
    const bool live[NTW] = {
        (wv * NTW + 0) * 16 < EHID, (wv * NTW + 1) * 16 < EHID,
        (wv * NTW + 2) * 16 < EHID, (wv * NTW + 3) * 16 < EHID,
        (wv * NTW + 4) * 16 < EHID };
    const _Float16* wb = w1ks + wv * (NTW * 512) + cl16 * 32 + h4 * 8;

    half8 bf0[NTW], bf1[NTW];
    #pragma unroll
    for (int nt = 0; nt < NTW; ++nt)
        if (live[nt]) bf0[nt] = *(const half8*)(wb + nt * 512);
    __builtin_amdgcn_sched_barrier(0);

    #pragma unroll
    for (int s = 0; s < NSLICE; ++s) {
        // issue next slice's B loads (into the idle buffer)
        if (s + 1 < NSLICE) {
            const _Float16* bsrc = wb + (long long)(s + 1) * (NP * 32);
            if (s & 1) {
                #pragma unroll
                for (int nt = 0; nt < NTW; ++nt)
                    if (live[nt]) bf0[nt] = *(const half8*)(bsrc + nt * 512);
            } else {
                #pragma unroll
                for (int nt = 0; nt < NTW; ++nt)
                    if (live[nt]) bf1[nt] = *(const half8*)(bsrc + nt * 512);
            }
        }
        // fence: loads above may NOT move below this point
        __builtin_amdgcn_sched_barrier(0);

        const int G = s * 4 + h4;
        half8 af[2];
        #pragma unroll
        for (int mt = 0; mt < 2; ++mt)
            af[mt] = *(const half8*)(lds_A + (mt * 16 + cl16) * KPA + G * 8);
        #pragma unroll
        for (int nt = 0; nt < NTW; ++nt)
            if (live[nt]) {
                half8 b = (s & 1) ? bf1[nt] : bf0[nt];
                #pragma unroll
                for (int mt = 0; mt < 2; ++mt)
                    acc[mt][nt] = __builtin_amdgcn_mfma_f32_16x16x32_f16(
                                      af[mt], b, acc[mt][nt], 0, 0, 0);
            }
    }

    // ---- prefetch GEMM2 B-frags; latency hides under the epilogue
    half8 bq[5];
    {
        const int kq = wv >> 1;
        #pragma unroll
        for (int k5 = 0; k5 < 5; ++k5)
            bq[k5] = *(const half8*)(w2t + cl16 * HIDP + (kq * 5 + k5) * 32 + h4 * 8);
    }
    __syncthreads();   // all GEMM1 LDS reads done; union region becomes hid

    // ---- epilogue 1: fast silu -> fp16 hid [32][648] plain
    #pragma unroll
    for (int nt = 0; nt < NTW; ++nt) {
        int hcol = (wv * NTW + nt) * 16 + cl16;   // < 640
        float bias = (hcol < EHID) ? b1[hcol] : 0.f;
        #pragma unroll
        for (int mt = 0; mt < 2; ++mt) {
            #pragma unroll
            for (int r = 0; r < 4; ++r) {
                int edge = mt * 16 + h4 * 4 + r;  // 0..31
                float v = (hcol < EHID) ? silu_f(acc[mt][nt][r] + bias) : 0.f;
                lds_H[edge * HIDPA + hcol] = (_Float16)v;
            }
        }
    }
    __syncthreads();

    // ---- GEMM2: [32 x 640] @ [640 x 16], 8 waves (2 halves x 4 K-quarters)
    {
        const int eh = wv & 1;
        const int kq = wv >> 1;
        f32x4 acc2 = {};
        const int oc = cl16;
        const int edgeA = eh * 16 + oc;
        #pragma unroll
        for (int k5 = 0; k5 < 5; ++k5) {
            int G2 = (kq * 5 + k5) * 4 + h4;      // 0..79
            const half8 a = *(const half8*)(lds_H + edgeA * HIDPA + G2 * 8);
            acc2 = __builtin_amdgcn_mfma_f32_16x16x32_f16(a, bq[k5], acc2, 0, 0, 0);
        }
        #pragma unroll
        for (int r = 0; r < 4; ++r)
            part[kq][eh * 16 + h4 * 4 + r][cl16] = acc2[r];
    }
    __syncthreads();

    // ---- final: sum partials, silu, LN(16), atomic scatter (waves 0,1)
    if (wv < 2) {
        const int eh = wv;
        const int oc = cl16;
        float g = g1[oc], bb = bb1[oc], b2v = b2[oc];
        #pragma unroll
        for (int r = 0; r < 4; ++r) {
            int edge = eh * 16 + h4 * 4 + r;
            float v = part[0][edge][oc] + part[1][edge][oc]
                    + part[2][edge][oc] + part[3][edge][oc] + b2v;
            v = silu_f(v);
            float s = v, s2 = v * v;
            #pragma unroll
            for (int m = 8; m >= 1; m >>= 1) {
                s  += __shfl_xor(s,  m, 16);
                s2 += __shfl_xor(s2, m, 16);
            }
            float mean = s * (1.f / 16.f);
            float var  = s2 * (1.f / 16.f) - mean * mean;
            float outv = (v - mean) * rsqrtf(var + LNEPS) * g + bb;
            atomicAdd(&m_i[(long long)dst_s[edge] * M + oc], outv);
        }
    }
}

// ---------------- Node kernel (validated) -----------------------------------
__global__ __launch_bounds__(512, 4) void node_kernel(
    const _Float16* __restrict__ feats, const float* __restrict__ x,
    const float* __restrict__ m_i,
    const float* __restrict__ en2g, const float* __restrict__ en2b,
    const float* __restrict__ nn1g, const float* __restrict__ nn1b,
    const _Float16* __restrict__ w1ks2, const float* __restrict__ b1,
    const _Float16* __restrict__ w2ks, const float* __restrict__ b2,
    const float* __restrict__ nn2g, const float* __restrict__ nn2b,
    float* __restrict__ out)
{
    __shared__ __align__(16) _Float16 smem[NPB2 * NHIDP];  // 42240 B (union)
    _Float16* lds_A = smem;   // [80][168]
    _Float16* lds_H = smem;   // [80][264]
    __shared__ float rsum2[NPB2], rsq2[NPB2];

    const int t    = threadIdx.x;
    const int lane = t & 63;
    const int wv   = t >> 6;
    const int cl16 = lane & 15;
    const int h4   = lane >> 4;
    const long long nb = (long long)blockIdx.x * NPB2;

    if (t < NPB2) { rsum2[t] = 0.f; rsq2[t] = 0.f; }

    #pragma unroll
    for (int p = 0; p < 5; ++p) {
        int nl = p * 16 + (t >> 5);
        int l  = t & 31;
        half4 v4 = *(const half4*)(feats + (nb + nl) * F + l * 4);
        float v[4]; float s = 0.f, s2 = 0.f;
        #pragma unroll
        for (int i = 0; i < 4; ++i) {
            v[i] = (float)v4[i]; s += v[i]; s2 += v[i]*v[i];
        }
        #pragma unroll
        for (int m = 16; m >= 1; m >>= 1) {
            s  += __shfl_xor(s,  m, 32);
            s2 += __shfl_xor(s2, m, 32);
        }
        float mean = s * (1.f/128.f);
        float var  = s2 * (1.f/128.f) - mean*mean;
        float rs   = rsqrtf(var + LNEPS);
        half4 w;
        #pragma unroll
        for (int i = 0; i < 4; ++i) {
            int c = l * 4 + i;
            w[i] = (_Float16)((v[i] - mean) * rs * nn1g[c] + nn1b[c]);
        }
        *(half4*)(lds_A + nl * NK1P + l * 4) = w;
    }
    for (int i = t; i < NPB2 * M; i += 512) {
        int nl = i >> 4, oc = i & 15;
        float v = m_i[(nb + nl) * M + oc];
        float a = v, a2 = v * v;
        #pragma unroll
        for (int m = 8; m >= 1; m >>= 1) {
            a  += __shfl_xor(a,  m, 16);
            a2 += __shfl_xor(a2, m, 16);
        }
        float mn = a * (1.f/16.f);
        float vr = a2 * (1.f/16.f) - mn*mn;
        float lv = (v - mn) * rsqrtf(vr + LNEPS) * en2g[oc] + en2b[oc];
        lds_A[nl * NK1P + 128 + oc] = (_Float16)lv;
    }
    for (int i = t; i < NPB2 * 16; i += 512) {
        int nl = i >> 4, j = i & 15;
        lds_A[nl * NK1P + 144 + j] = (_Float16)0.f;
    }
    __syncthreads();

    f32x4 acc[5][2] = {};
    #pragma unroll
    for (int s = 0; s < NSL2; ++s) {
        half8 bf[2];
        #pragma unroll
        for (int nt = 0; nt < 2; ++nt)
            bf[nt] = *(const half8*)(w1ks2 + s * (NHID * 32)
                                     + (wv * 2 + nt) * 512 + cl16 * 32 + h4 * 8);
        const int G = s * 4 + h4;
        half8 af[5];
        #pragma unroll
        for (int mt = 0; mt < 5; ++mt)
            af[mt] = *(const half8*)(lds_A + (mt * 16 + cl16) * NK1P + G * 8);
        #pragma unroll
        for (int nt = 0; nt < 2; ++nt) {
            #pragma unroll
            for (int mt = 0; mt < 5; ++mt)
                acc[mt][nt] = __builtin_amdgcn_mfma_f32_16x16x32_f16(
                                  af[mt], bf[nt], acc[mt][nt], 0, 0, 0);
        }
    }
    __syncthreads();

    #pragma unroll
    for (int nt = 0; nt < 2; ++nt) {
        int hcol = (wv * 2 + nt) * 16 + cl16;
        float bias = b1[hcol];
        #pragma unroll
        for (int mt = 0; mt < 5; ++mt) {
            #pragma unroll
            for (int r = 0; r < 4; ++r) {
                int row = mt * 16 + h4 * 4 + r;
                float v = silu_f(acc[mt][nt][r] + bias);
                lds_H[row * NHIDP + hcol] = (_Float16)v;
            }
        }
    }
    __syncthreads();

    f32x4 acc2[5] = {};
    const int col = wv * 16 + cl16;
    #pragma unroll
    for (int s = 0; s < 8; ++s) {
        const half8 b = *(const half8*)(w2ks + s * (F * 32) + col * 32 + h4 * 8);
        const int G2 = s * 4 + h4;
        #pragma unroll
        for (int mt = 0; mt < 5; ++mt) {
            int row = mt * 16 + cl16;
            const half8 a = *(const half8*)(lds_H + row * NHIDP + G2 * 8);
            acc2[mt] = __builtin_amdgcn_mfma_f32_16x16x32_f16(a, b, acc2[mt], 0, 0, 0);
        }
    }

    float y[5][4];
    float b2v = b2[col];
    #pragma unroll
    for (int mt = 0; mt < 5; ++mt) {
        #pragma unroll
        for (int r = 0; r < 4; ++r) {
            float v = acc2[mt][r] + b2v;
            y[mt][r] = v;
            float s = v, s2 = v * v;
            #pragma unroll
            for (int m = 8; m >= 1; m >>= 1) {
                s  += __shfl_xor(s,  m, 16);
                s2 += __shfl_xor(s2, m, 16);
            }
            if (cl16 == 0) {
                int row = mt * 16 + h4 * 4 + r;
                atomicAdd(&rsum2[row], s);
                atomicAdd(&rsq2[row],  s2);
            }
        }
    }
    __syncthreads();

    float gcol2 = nn2g[col], bcol2 = nn2b[col];
    #pragma unroll
    for (int mt = 0; mt < 5; ++mt) {
        #pragma unroll
        for (int r = 0; r < 4; ++r) {
            int row = mt * 16 + h4 * 4 + r;
            long long node = nb + row;
            float mn = rsum2[row] * (1.f/128.f);
            float vr = rsq2[row] * (1.f/128.f) - mn*mn;
            float rs = rsqrtf(vr + LNEPS);
            float res = x[node * ROW + POSD + col];
            out[node * ROW + POSD + col] = res + (y[mt][r] - mn) * rs * gcol2 + bcol2;
        }
    }
    for (int i = t; i < NPB2 * POSD; i += 512) {
        int nl = i / 3, c = i - nl * 3;
        long long node = nb + nl;
        out[node * ROW + c] = x[node * ROW + c];
    }
}

extern "C" void kernel_launch(void* const* d_in, const int* in_sizes, int n_in,
                              void* d_out, int out_size, void* d_ws, size_t ws_size,
                              hipStream_t stream) {
    const float* x    = (const float*)d_in[0];
    const int*   ei   = (const int*)d_in[1];
    const float* e_w1 = (const float*)d_in[2];
    const float* e_b1 = (const float*)d_in[3];
    const float* e_w2 = (const float*)d_in[4];
    const float* e_b2 = (const float*)d_in[5];
    const float* en1g = (const float*)d_in[6];
    const float* en1b = (const float*)d_in[7];
    const float* en2g = (const float*)d_in[8];
    const float* en2b = (const float*)d_in[9];
    const float* nn1g = (const float*)d_in[10];
    const float* nn1b = (const float*)d_in[11];
    const float* n_w1 = (const float*)d_in[12];
    const float* n_b1 = (const float*)d_in[13];
    const float* n_w2 = (const float*)d_in[14];
    const float* n_b2 = (const float*)d_in[15];
    const float* nn2g = (const float*)d_in[16];
    const float* nn2b = (const float*)d_in[17];
    float* out = (float*)d_out;

    char* ws = (char*)d_ws;
    float*    m_i   = (float*)ws;                     //  6,400,000 B
    _Float16* w1ks  = (_Float16*)(ws + WS_W1KS);      //    409,600 B
    _Float16* w2t   = (_Float16*)(ws + WS_W2T);       //     20,480 B
    _Float16* feats = (_Float16*)(ws + WS_FEATS);     // 25,600,000 B
    _Float16* w1ks2 = (_Float16*)(ws + WS_W1KS2);     //     81,920 B
    _Float16* w2ks  = (_Float16*)(ws + WS_W2KS);      //     65,536 B

    hipMemsetAsync(m_i, 0, (size_t)N_NODES * M * sizeof(float), stream);
    prep_weights<<<840, 256, 0, stream>>>(e_w1, e_w2, w1ks, w2t);
    prep_weights_node<<<288, 256, 0, stream>>>(n_w1, n_w2, w1ks2, w2ks);
    prep_feats<<<(N_NODES * F + 255) / 256, 256, 0, stream>>>(x, feats);
    edge_kernel<<<N_EDGES / EPB, 512, 0, stream>>>(
        feats, x, ei, w1ks, e_b1, w2t, e_b2, en1g, en1b, m_i);
    node_kernel<<<N_NODES / NPB2, 512, 0, stream>>>(
        feats, x, m_i, en2g, en2b, nn1g, nn1b, w1ks2, n_b1, w2ks, n_b2, nn2g, nn2b, out);
}

// Round 24
// 490.061 us; speedup vs baseline: 1.1175x; 1.1175x over previous
//
#include <hip/hip_runtime.h>
#include <math.h>

#define N_NODES 100000
#define N_EDGES 400000
#define POSD 3
#define F 128
#define M 16
#define EIN 289
#define EHID 578
#define NIN 144
#define NHID 256
#define ROW 131
#define LNEPS 1e-5f

// edge GEMM dims — plain padded LDS, no swizzle
#define KPA 328     // A row stride: 320+8 (free 2-way bank alias)
#define NP 640
#define EPB 32      // edges per block (512 threads, 8 waves)
#define NSLICE 10
#define NTW 5
#define HIDP 640    // w2t K stride
#define HIDPA 648   // hid LDS row stride: 640+8

// node kernel — plain padded LDS (validated)
#define NPB2 80
#define NK1P 168
#define NSL2 5
#define NHIDP 264

// ws offsets (bytes)
#define WS_W1KS   6400000
#define WS_W2T    6809600
#define WS_FEATS  6830080
#define WS_W1KS2  32430080
#define WS_W2KS   32512000

typedef _Float16 half8 __attribute__((ext_vector_type(8)));
typedef _Float16 half4 __attribute__((ext_vector_type(4)));
typedef float f32x4 __attribute__((ext_vector_type(4)));

__device__ __forceinline__ float silu_f(float v) {
    // fp32 rcp approx: result rounds to fp16 right after, 1-ulp rcp is free
    return v * __builtin_amdgcn_rcpf(1.f + __expf(-v));
}

// ---------------- prep: x feats -> fp16 [N][128] ---------------------------
__global__ __launch_bounds__(256) void prep_feats(
    const float* __restrict__ x, _Float16* __restrict__ feats)
{
    long long i = (long long)blockIdx.x * 256 + threadIdx.x;
    if (i < (long long)N_NODES * F) {
        int n = (int)(i >> 7), k = (int)(i & 127);
        feats[i] = (_Float16)x[(long long)n * ROW + POSD + k];
    }
}

// ---------------- prep: edge weights fp16 -----------------------------------
__global__ __launch_bounds__(256) void prep_weights(
    const float* __restrict__ w1, const float* __restrict__ w2,
    _Float16* __restrict__ w1ks, _Float16* __restrict__ w2t)
{
    long long idx = (long long)blockIdx.x * 256 + threadIdx.x;
    const long long n1 = (long long)NSLICE * NP * 32;  // 204800
    if (idx < n1) {
        int s   = (int)(idx / (NP * 32));
        int rem = (int)(idx - (long long)s * (NP * 32));
        int c   = rem >> 5;
        int kk  = rem & 31;
        int k   = s * 32 + kk;
        float v = (k < EIN && c < EHID) ? w1[(long long)k * EHID + c] : 0.f;
        w1ks[idx] = (_Float16)v;   // (slice, col, kk) plain
    } else {
        long long j = idx - n1;
        if (j < (long long)M * HIDP) {
            int oc = (int)(j / HIDP);
            int k  = (int)(j - (long long)oc * HIDP);
            float v = (k < EHID) ? w2[(long long)k * M + oc] : 0.f;
            w2t[j] = (_Float16)v;
        }
    }
}

// ---------------- prep: node weights fp16 K-sliced --------------------------
__global__ __launch_bounds__(256) void prep_weights_node(
    const float* __restrict__ w1, const float* __restrict__ w2,
    _Float16* __restrict__ w1ks2, _Float16* __restrict__ w2ks)
{
    int idx = blockIdx.x * 256 + threadIdx.x;
    const int n1 = NSL2 * 256 * 32;  // 40960
    if (idx < n1) {
        int s = idx >> 13, rem = idx & 8191;
        int c = rem >> 5, kk = rem & 31;
        int k = s * 32 + kk;
        w1ks2[idx] = (_Float16)((k < NIN) ? w1[k * NHID + c] : 0.f);
    } else if (idx < n1 + 8 * 128 * 32) {
        int j = idx - n1;
        int s = j >> 12, rem = j & 4095;
        int c = rem >> 5, kk = rem & 31;
        int k = s * 32 + kk;
        w2ks[j] = (_Float16)w2[k * F + c];
    }
}

// ---------------- Edge kernel (best measured: 452 us config) ----------------
// 16x16x32 layout: A row = lane&15, k-grp = lane>>4; B col = lane&15;
// C/D col = lane&15, row = (lane>>4)*4 + reg.
__global__ __launch_bounds__(512, 4) void edge_kernel(
    const _Float16* __restrict__ feats, const float* __restrict__ x,
    const int* __restrict__ ei,
    const _Float16* __restrict__ w1ks, const float* __restrict__ b1,
    const _Float16* __restrict__ w2t, const float* __restrict__ b2,
    const float* __restrict__ g1, const float* __restrict__ bb1,
    float* __restrict__ m_i)
{
    __shared__ __align__(16) _Float16 smem[EPB * HIDPA];  // 41472 B (union)
    _Float16* lds_A = smem;     // [32][328] plain, first 20992 B
    _Float16* lds_H = smem;     // [32][648] plain, full
    __shared__ float part[4][EPB][M];                     // 8192 B GEMM2 partials
    __shared__ int   src_s[EPB], dst_s[EPB];
    __shared__ float d_s[EPB];

    const int t    = threadIdx.x;
    const int lane = t & 63;
    const int wv   = t >> 6;       // 0..7
    const int cl16 = lane & 15;
    const int h4   = lane >> 4;
    const long long ebase = (long long)blockIdx.x * EPB;

    if (t < EPB) {
        int s = ei[ebase + t];
        int d = ei[(long long)N_EDGES + ebase + t];
        src_s[t] = s; dst_s[t] = d;
        float dx = x[(long long)s*ROW+0] - x[(long long)d*ROW+0];
        float dy = x[(long long)s*ROW+1] - x[(long long)d*ROW+1];
        float dz = x[(long long)s*ROW+2] - x[(long long)d*ROW+2];
        d_s[t] = dx*dx + dy*dy + dz*dz;
    }
    __syncthreads();

    // ---- A staging: feats, 16B half8 loads, plain 16B LDS writes
    for (int i = t; i < EPB * 32; i += 512) {
        int row = i >> 5, g = i & 31;
        int node = (g < 16) ? dst_s[row] : src_s[row];
        half8 v = *(const half8*)(feats + (long long)node * F + ((g & 15) << 3));
        *(half8*)(lds_A + row * KPA + (g << 3)) = v;
    }
    // ---- A staging: rbf + d + pad, branch-free
    for (int i = t; i < EPB * 64; i += 512) {
        int row = i >> 6, j = i & 63;
        float dv = d_s[row];
        float ds = ldexpf(dv, -(j & 15));
        float v = (j < 16) ? __sinf(ds) : (j < 32) ? __cosf(ds)
                : (j == 32) ? dv : 0.f;
        lds_A[row * KPA + 256 + j] = (_Float16)v;
    }
    __syncthreads();

    // ---- GEMM1: [32 x 320] @ [320 x 640]; B from L2; dead tiles skipped
    f32x4 acc[2][NTW] = {};
    const bool live[NTW] = {
        (wv * NTW + 0) * 16 < EHID, (wv * NTW + 1) * 16 < EHID,
        (wv * NTW + 2) * 16 < EHID, (wv * NTW + 3) * 16 < EHID,
        (wv * NTW + 4) * 16 < EHID };
    #pragma unroll
    for (int s = 0; s < NSLICE; ++s) {
        half8 bf[NTW];
        #pragma unroll
        for (int nt = 0; nt < NTW; ++nt)
            if (live[nt])
                bf[nt] = *(const half8*)(w1ks + (long long)s * (NP * 32)
                                         + (wv * NTW + nt) * 512 + cl16 * 32 + h4 * 8);
        const int G = s * 4 + h4;
        half8 af[2];
        #pragma unroll
        for (int mt = 0; mt < 2; ++mt)
            af[mt] = *(const half8*)(lds_A + (mt * 16 + cl16) * KPA + G * 8);
        #pragma unroll
        for (int nt = 0; nt < NTW; ++nt)
            if (live[nt]) {
                #pragma unroll
                for (int mt = 0; mt < 2; ++mt)
                    acc[mt][nt] = __builtin_amdgcn_mfma_f32_16x16x32_f16(
                                      af[mt], bf[nt], acc[mt][nt], 0, 0, 0);
            }
    }

    // ---- prefetch GEMM2 B-frags; latency hides under the epilogue
    half8 bq[5];
    {
        const int kq = wv >> 1;
        #pragma unroll
        for (int k5 = 0; k5 < 5; ++k5)
            bq[k5] = *(const half8*)(w2t + cl16 * HIDP + (kq * 5 + k5) * 32 + h4 * 8);
    }
    __syncthreads();   // all GEMM1 LDS reads done; union region becomes hid

    // ---- epilogue 1: fast silu -> fp16 hid [32][648] plain
    #pragma unroll
    for (int nt = 0; nt < NTW; ++nt) {
        int hcol = (wv * NTW + nt) * 16 + cl16;   // < 640
        float bias = (hcol < EHID) ? b1[hcol] : 0.f;
        #pragma unroll
        for (int mt = 0; mt < 2; ++mt) {
            #pragma unroll
            for (int r = 0; r < 4; ++r) {
                int edge = mt * 16 + h4 * 4 + r;  // 0..31
                float v = (hcol < EHID) ? silu_f(acc[mt][nt][r] + bias) : 0.f;
                lds_H[edge * HIDPA + hcol] = (_Float16)v;
            }
        }
    }
    __syncthreads();

    // ---- GEMM2: [32 x 640] @ [640 x 16], 8 waves (2 halves x 4 K-quarters)
    {
        const int eh = wv & 1;
        const int kq = wv >> 1;
        f32x4 acc2 = {};
        const int oc = cl16;
        const int edgeA = eh * 16 + oc;
        #pragma unroll
        for (int k5 = 0; k5 < 5; ++k5) {
            int G2 = (kq * 5 + k5) * 4 + h4;      // 0..79
            const half8 a = *(const half8*)(lds_H + edgeA * HIDPA + G2 * 8);
            acc2 = __builtin_amdgcn_mfma_f32_16x16x32_f16(a, bq[k5], acc2, 0, 0, 0);
        }
        #pragma unroll
        for (int r = 0; r < 4; ++r)
            part[kq][eh * 16 + h4 * 4 + r][cl16] = acc2[r];
    }
    __syncthreads();

    // ---- final: sum partials, silu, LN(16), atomic scatter (waves 0,1)
    if (wv < 2) {
        const int eh = wv;
        const int oc = cl16;
        float g = g1[oc], bb = bb1[oc], b2v = b2[oc];
        #pragma unroll
        for (int r = 0; r < 4; ++r) {
            int edge = eh * 16 + h4 * 4 + r;
            float v = part[0][edge][oc] + part[1][edge][oc]
                    + part[2][edge][oc] + part[3][edge][oc] + b2v;
            v = silu_f(v);
            float s = v, s2 = v * v;
            #pragma unroll
            for (int m = 8; m >= 1; m >>= 1) {
                s  += __shfl_xor(s,  m, 16);
                s2 += __shfl_xor(s2, m, 16);
            }
            float mean = s * (1.f / 16.f);
            float var  = s2 * (1.f / 16.f) - mean * mean;
            float outv = (v - mean) * rsqrtf(var + LNEPS) * g + bb;
            atomicAdd(&m_i[(long long)dst_s[edge] * M + oc], outv);
        }
    }
}

// ---------------- Node kernel (validated) -----------------------------------
__global__ __launch_bounds__(512, 4) void node_kernel(
    const _Float16* __restrict__ feats, const float* __restrict__ x,
    const float* __restrict__ m_i,
    const float* __restrict__ en2g, const float* __restrict__ en2b,
    const float* __restrict__ nn1g, const float* __restrict__ nn1b,
    const _Float16* __restrict__ w1ks2, const float* __restrict__ b1,
    const _Float16* __restrict__ w2ks, const float* __restrict__ b2,
    const float* __restrict__ nn2g, const float* __restrict__ nn2b,
    float* __restrict__ out)
{
    __shared__ __align__(16) _Float16 smem[NPB2 * NHIDP];  // 42240 B (union)
    _Float16* lds_A = smem;   // [80][168]
    _Float16* lds_H = smem;   // [80][264]
    __shared__ float rsum2[NPB2], rsq2[NPB2];

    const int t    = threadIdx.x;
    const int lane = t & 63;
    const int wv   = t >> 6;
    const int cl16 = lane & 15;
    const int h4   = lane >> 4;
    const long long nb = (long long)blockIdx.x * NPB2;

    if (t < NPB2) { rsum2[t] = 0.f; rsq2[t] = 0.f; }

    #pragma unroll
    for (int p = 0; p < 5; ++p) {
        int nl = p * 16 + (t >> 5);
        int l  = t & 31;
        half4 v4 = *(const half4*)(feats + (nb + nl) * F + l * 4);
        float v[4]; float s = 0.f, s2 = 0.f;
        #pragma unroll
        for (int i = 0; i < 4; ++i) {
            v[i] = (float)v4[i]; s += v[i]; s2 += v[i]*v[i];
        }
        #pragma unroll
        for (int m = 16; m >= 1; m >>= 1) {
            s  += __shfl_xor(s,  m, 32);
            s2 += __shfl_xor(s2, m, 32);
        }
        float mean = s * (1.f/128.f);
        float var  = s2 * (1.f/128.f) - mean*mean;
        float rs   = rsqrtf(var + LNEPS);
        half4 w;
        #pragma unroll
        for (int i = 0; i < 4; ++i) {
            int c = l * 4 + i;
            w[i] = (_Float16)((v[i] - mean) * rs * nn1g[c] + nn1b[c]);
        }
        *(half4*)(lds_A + nl * NK1P + l * 4) = w;
    }
    for (int i = t; i < NPB2 * M; i += 512) {
        int nl = i >> 4, oc = i & 15;
        float v = m_i[(nb + nl) * M + oc];
        float a = v, a2 = v * v;
        #pragma unroll
        for (int m = 8; m >= 1; m >>= 1) {
            a  += __shfl_xor(a,  m, 16);
            a2 += __shfl_xor(a2, m, 16);
        }
        float mn = a * (1.f/16.f);
        float vr = a2 * (1.f/16.f) - mn*mn;
        float lv = (v - mn) * rsqrtf(vr + LNEPS) * en2g[oc] + en2b[oc];
        lds_A[nl * NK1P + 128 + oc] = (_Float16)lv;
    }
    for (int i = t; i < NPB2 * 16; i += 512) {
        int nl = i >> 4, j = i & 15;
        lds_A[nl * NK1P + 144 + j] = (_Float16)0.f;
    }
    __syncthreads();

    f32x4 acc[5][2] = {};
    #pragma unroll
    for (int s = 0; s < NSL2; ++s) {
        half8 bf[2];
        #pragma unroll
        for (int nt = 0; nt < 2; ++nt)
            bf[nt] = *(const half8*)(w1ks2 + s * (NHID * 32)
                                     + (wv * 2 + nt) * 512 + cl16 * 32 + h4 * 8);
        const int G = s * 4 + h4;
        half8 af[5];
        #pragma unroll
        for (int mt = 0; mt < 5; ++mt)
            af[mt] = *(const half8*)(lds_A + (mt * 16 + cl16) * NK1P + G * 8);
        #pragma unroll
        for (int nt = 0; nt < 2; ++nt) {
            #pragma unroll
            for (int mt = 0; mt < 5; ++mt)
                acc[mt][nt] = __builtin_amdgcn_mfma_f32_16x16x32_f16(
                                  af[mt], bf[nt], acc[mt][nt], 0, 0, 0);
        }
    }
    __syncthreads();

    #pragma unroll
    for (int nt = 0; nt < 2; ++nt) {
        int hcol = (wv * 2 + nt) * 16 + cl16;
        float bias = b1[hcol];
        #pragma unroll
        for (int mt = 0; mt < 5; ++mt) {
            #pragma unroll
            for (int r = 0; r < 4; ++r) {
                int row = mt * 16 + h4 * 4 + r;
                float v = silu_f(acc[mt][nt][r] + bias);
                lds_H[row * NHIDP + hcol] = (_Float16)v;
            }
        }
    }
    __syncthreads();

    f32x4 acc2[5] = {};
    const int col = wv * 16 + cl16;
    #pragma unroll
    for (int s = 0; s < 8; ++s) {
        const half8 b = *(const half8*)(w2ks + s * (F * 32) + col * 32 + h4 * 8);
        const int G2 = s * 4 + h4;
        #pragma unroll
        for (int mt = 0; mt < 5; ++mt) {
            int row = mt * 16 + cl16;
            const half8 a = *(const half8*)(lds_H + row * NHIDP + G2 * 8);
            acc2[mt] = __builtin_amdgcn_mfma_f32_16x16x32_f16(a, b, acc2[mt], 0, 0, 0);
        }
    }

    float y[5][4];
    float b2v = b2[col];
    #pragma unroll
    for (int mt = 0; mt < 5; ++mt) {
        #pragma unroll
        for (int r = 0; r < 4; ++r) {
            float v = acc2[mt][r] + b2v;
            y[mt][r] = v;
            float s = v, s2 = v * v;
            #pragma unroll
            for (int m = 8; m >= 1; m >>= 1) {
                s  += __shfl_xor(s,  m, 16);
                s2 += __shfl_xor(s2, m, 16);
            }
            if (cl16 == 0) {
                int row = mt * 16 + h4 * 4 + r;
                atomicAdd(&rsum2[row], s);
                atomicAdd(&rsq2[row],  s2);
            }
        }
    }
    __syncthreads();

    float gcol2 = nn2g[col], bcol2 = nn2b[col];
    #pragma unroll
    for (int mt = 0; mt < 5; ++mt) {
        #pragma unroll
        for (int r = 0; r < 4; ++r) {
            int row = mt * 16 + h4 * 4 + r;
            long long node = nb + row;
            float mn = rsum2[row] * (1.f/128.f);
            float vr = rsq2[row] * (1.f/128.f) - mn*mn;
            float rs = rsqrtf(vr + LNEPS);
            float res = x[node * ROW + POSD + col];
            out[node * ROW + POSD + col] = res + (y[mt][r] - mn) * rs * gcol2 + bcol2;
        }
    }
    for (int i = t; i < NPB2 * POSD; i += 512) {
        int nl = i / 3, c = i - nl * 3;
        long long node = nb + nl;
        out[node * ROW + c] = x[node * ROW + c];
    }
}

extern "C" void kernel_launch(void* const* d_in, const int* in_sizes, int n_in,
                              void* d_out, int out_size, void* d_ws, size_t ws_size,
                              hipStream_t stream) {
    const float* x    = (const float*)d_in[0];
    const int*   ei   = (const int*)d_in[1];
    const float* e_w1 = (const float*)d_in[2];
    const float* e_b1 = (const float*)d_in[3];
    const float* e_w2 = (const float*)d_in[4];
    const float* e_b2 = (const float*)d_in[5];
    const float* en1g = (const float*)d_in[6];
    const float* en1b = (const float*)d_in[7];
    const float* en2g = (const float*)d_in[8];
    const float* en2b = (const float*)d_in[9];
    const float* nn1g = (const float*)d_in[10];
    const float* nn1b = (const float*)d_in[11];
    const float* n_w1 = (const float*)d_in[12];
    const float* n_b1 = (const float*)d_in[13];
    const float* n_w2 = (const float*)d_in[14];
    const float* n_b2 = (const float*)d_in[15];
    const float* nn2g = (const float*)d_in[16];
    const float* nn2b = (const float*)d_in[17];
    float* out = (float*)d_out;

    char* ws = (char*)d_ws;
    float*    m_i   = (float*)ws;                     //  6,400,000 B
    _Float16* w1ks  = (_Float16*)(ws + WS_W1KS);      //    409,600 B
    _Float16* w2t   = (_Float16*)(ws + WS_W2T);       //     20,480 B
    _Float16* feats = (_Float16*)(ws + WS_FEATS);     // 25,600,000 B
    _Float16* w1ks2 = (_Float16*)(ws + WS_W1KS2);     //     81,920 B
    _Float16* w2ks  = (_Float16*)(ws + WS_W2KS);      //     65,536 B

    hipMemsetAsync(m_i, 0, (size_t)N_NODES * M * sizeof(float), stream);
    prep_weights<<<840, 256, 0, stream>>>(e_w1, e_w2, w1ks, w2t);
    prep_weights_node<<<288, 256, 0, stream>>>(n_w1, n_w2, w1ks2, w2ks);
    prep_feats<<<(N_NODES * F + 255) / 256, 256, 0, stream>>>(x, feats);
    edge_kernel<<<N_EDGES / EPB, 512, 0, stream>>>(
        feats, x, ei, w1ks, e_b1, w2t, e_b2, en1g, en1b, m_i);
    node_kernel<<<N_NODES / NPB2, 512, 0, stream>>>(
        feats, x, m_i, en2g, en2b, nn1g, nn1b, w1ks2, n_b1, w2ks, n_b2, nn2g, nn2b, out);
}